// Round 13
// baseline (1046.206 us; speedup 1.0000x reference)
//
#include <hip/hip_runtime.h>
#include <math.h>

#define S    256
#define Hp   288
#define C    32
#define KY   12
#define NK   24
#define Bn   8
#define PI_D 3.14159265358979323846264338327950288

// workspace offsets (in floats)
#define SZ_TW  (NK*Hp*2)                // 13824  [k][x] layout, k<24
#define OFF_TW 0
#define OFF_TWT (OFF_TW + SZ_TW)
#define SZ_TWT (Hp*KY*2)                // 6912   [y][k][2] transposed, k<12
#define OFF_H  (OFF_TWT + SZ_TWT)
#define SZ_H   (Bn*C*Hp*Hp)             // 21233664
#define OFF_Y  (OFF_H + SZ_H)
#define SZ_Y   (Bn*C*Hp*KY*2)           // 1769472
#define OFF_X  (OFF_Y + SZ_Y)
#define SZ_X   (Bn*C*NK*KY*2)           // 147456 (one half-partial)
#define OFF_Z  (OFF_X + 2*SZ_X)
#define SZ_Z   (Bn*Hp*C*KY*2)           // 1769472
#define OFF_T  (OFF_Z + SZ_Z)
#define SZ_T   (Bn*S*S*2)               // 1048576

#define GELU(v) (0.5f*(v)*(1.0f+erff((v)*0.70710678118654752f)))
#define SCHED_FENCE() __builtin_amdgcn_sched_barrier(0)

#if __has_builtin(__builtin_amdgcn_global_load_lds)
#define HAS_ASYNC 1
#define ASYNC_CP16(dst, src) \
    __builtin_amdgcn_global_load_lds((const __attribute__((address_space(1))) void*)(src), \
                                     (__attribute__((address_space(3))) void*)(dst), 16, 0, 0)
#else
#define HAS_ASYNC 0
#endif

// twiddle tables: tw[k][x] (k<24, both signs) and transposed twT[x][k][2] (k<12)
__global__ void k_tw(float* __restrict__ tw, float* __restrict__ twT) {
    int i = blockIdx.x * 256 + threadIdx.x;
    if (i >= NK * Hp) return;
    int k = i / Hp, xx = i % Hp;
    int f = (k < KY) ? k : (k + 264);
    int m = (f * xx) % Hp;                        // exact integer phase reduction
    double th = (2.0 * PI_D * (double)m) / (double)Hp;
    float c = (float)cos(th), s = (float)sin(th);
    tw[2 * i] = c; tw[2 * i + 1] = s;
    if (k < KY) { twT[xx * 24 + 2 * k] = c; twT[xx * 24 + 2 * k + 1] = s; }
}

// embed main body, templated on quarter Q (wave-uniform: Q = tid>>6).
template<int Q>
__device__ __forceinline__ void embed_body(
        const float* __restrict__ xs, const float* __restrict__ twq,
        float* __restrict__ h, size_t rowbase, int o, int g,
        float w0, float w1, float w2, float bb, float gx,
        float* pr, float* pi) {
    #pragma unroll 1
    for (int c3 = 0; c3 < 3; ++c3) {
        int ybase = g * 36 + c3 * 12;
        int rowq  = (g & 1) * 36 + c3 * 12;
        float acc[12];
        #pragma unroll
        for (int j = 0; j < 12; ++j) {
            int y = ybase + j;
            acc[j] = (y < S) ? (w0 * xs[y < S ? y : 0] + w1 * gx + w2 * (y * (1.0f / 255.0f)) + bb) : 0.f;
        }
        float* hw = h + rowbase + (size_t)o * 82944 + ybase;
        #pragma unroll
        for (int q = 0; q < 3; ++q)
            *(float4*)&hw[4 * q] = make_float4(acc[4*q], acc[4*q+1], acc[4*q+2], acc[4*q+3]);
        SCHED_FENCE();
        #pragma unroll
        for (int jp = 0; jp < 6; ++jp) {
            #pragma unroll
            for (int u = 0; u < 2; ++u) {
                int j = jp * 2 + u;
                const float* tg = twq + (rowq + j) * 24;
                float tc[24];
                #pragma unroll
                for (int q = 0; q < 6; ++q) *(float4*)&tc[4 * q] = *(const float4*)&tg[4 * q];
                float v = acc[j];
                pr[0] += v;                          // k=0: (1,0) in all quarters
                #pragma unroll
                for (int k = 1; k < 12; ++k) {
                    const int e = (k * Q) & 3;
                    float c = tc[2 * k], s = tc[2 * k + 1];
                    if      (e == 0) { pr[k] += v * c; pi[k] -= v * s; }
                    else if (e == 1) { pr[k] -= v * s; pi[k] -= v * c; }
                    else if (e == 2) { pr[k] -= v * c; pi[k] += v * s; }
                    else             { pr[k] += v * s; pi[k] += v * c; }
                }
            }
            SCHED_FENCE();
        }
    }
}

// gather + grid + fc0 + pad -> h row, fused forward DFT-y -> Y. (r11, best)
__global__ __launch_bounds__(256, 1) void k_embed(
        const float* __restrict__ xin, const int* __restrict__ d2v,
        const float* __restrict__ fw, const float* __restrict__ fb,
        const float* __restrict__ twT, float* __restrict__ h, float* __restrict__ Y) {
    __shared__ __align__(16) float xs[256];
    __shared__ __align__(16) float twq[1728];       // quarter table, rows y<72
    __shared__ __align__(16) float YP[3072];
    int x = blockIdx.x, b = blockIdx.y, tid = threadIdx.x;
    size_t rowbase = (size_t)b * 2654208 + (size_t)x * 288;
    if (x >= S) {                                   // pad rows: h=0, Y=0
        for (int i = tid; i < 32 * 72; i += 256) {
            int c = i / 72, q = i % 72;
            *(float4*)&h[rowbase + (size_t)c * 82944 + q * 4] = make_float4(0, 0, 0, 0);
        }
        for (int i = tid; i < 768; i += 256)
            Y[((size_t)(b * 32 + i / 24) * 288 + x) * 24 + (i % 24)] = 0.f;
        return;
    }
    for (int i = tid; i < 432; i += 256)
        *(float4*)&twq[4 * i] = *(const float4*)&twT[4 * i];
    xs[tid] = xin[b * 65536 + d2v[x * 256 + tid]];
    int o = tid & 31, g = tid >> 5;
    float w0 = fw[o * 3], w1 = fw[o * 3 + 1], w2 = fw[o * 3 + 2], bb = fb[o];
    float gx = x * (1.0f / 255.0f);
    __syncthreads();
    float pr[12], pi[12];
    #pragma unroll
    for (int k = 0; k < 12; ++k) { pr[k] = 0.f; pi[k] = 0.f; }
    switch (tid >> 6) {                              // quarter = wave id (uniform)
        case 0: embed_body<0>(xs, twq, h, rowbase, o, g, w0, w1, w2, bb, gx, pr, pi); break;
        case 1: embed_body<1>(xs, twq, h, rowbase, o, g, w0, w1, w2, bb, gx, pr, pi); break;
        case 2: embed_body<2>(xs, twq, h, rowbase, o, g, w0, w1, w2, bb, gx, pr, pi); break;
        default: embed_body<3>(xs, twq, h, rowbase, o, g, w0, w1, w2, bb, gx, pr, pi); break;
    }
    #pragma unroll
    for (int k = 0; k < 12; ++k) { pr[k] += __shfl_xor(pr[k], 32); pi[k] += __shfl_xor(pi[k], 32); }
    if ((tid & 32) == 0) {
        float* dst = YP + ((tid >> 6) * 32 + o) * 24;
        #pragma unroll
        for (int k = 0; k < 12; ++k) { dst[2 * k] = pr[k]; dst[2 * k + 1] = pi[k]; }
    }
    __syncthreads();
    for (int i = tid; i < 768; i += 256) {
        float s = YP[i] + YP[768 + i] + YP[1536 + i] + YP[2304 + i];
        Y[((size_t)(b * 32 + i / 24) * 288 + x) * 24 + (i % 24)] = s;
    }
}

// forward DFT along x, split into 2 x-half partials. X[half][b][c][k][ky]
__global__ __launch_bounds__(288) void k_dftx(const float* __restrict__ Y,
                                              const float* __restrict__ tw,
                                              float* __restrict__ X) {
    __shared__ __align__(16) float Ys[144 * 24];
    int c = blockIdx.x, b = blockIdx.y, half = blockIdx.z, tid = threadIdx.x;
    const float* Yb = Y + (size_t)(b * 32 + c) * 6912 + half * 3456;
    for (int i = tid; i < 864; i += 288)
        *(float4*)&Ys[4 * i] = *(const float4*)&Yb[4 * i];
    __syncthreads();
    int k = tid / 12, ky = tid % 12;
    const float* twk = tw + k * 576 + half * 288;
    float xr = 0.f, xi = 0.f;
    #pragma unroll 4
    for (int xx = 0; xx < 144; ++xx) {
        float yr = Ys[xx * 24 + 2 * ky], yi = Ys[xx * 24 + 2 * ky + 1];
        float cc = twk[2 * xx], ss = twk[2 * xx + 1];
        xr += yr * cc + yi * ss;      // e^{-i t}
        xi += yi * cc - yr * ss;
    }
    size_t oo = (size_t)half * SZ_X + ((size_t)(b * 32 + c) * 288 + tid) * 2;
    X[oo] = xr; X[oo + 1] = xi;
}

// fused spec + inverse-DFT-x (r12 kernel, kept).
__global__ __launch_bounds__(384) void k_specidft(
        const float* __restrict__ X,
        const float* __restrict__ w1r, const float* __restrict__ w1i,
        const float* __restrict__ w2r, const float* __restrict__ w2i,
        const float* __restrict__ tw, float* __restrict__ Z, int l) {
    __shared__ __align__(16) float Os[576];
    int x0 = blockIdx.x * 32, c = blockIdx.y, b = blockIdx.z, tid = threadIdx.x;
    if (tid < 288) {
        int k = tid / 12, ky = tid % 12;
        int kk = (k < KY) ? k : (k - KY);
        const float* wr = (k < KY) ? w1r : w2r;
        const float* wi = (k < KY) ? w1i : w2i;
        size_t wbase = (size_t)l * 147456 + (size_t)c * 144 + kk * 12 + ky;
        size_t xbase = (size_t)b * 18432 + (k * 12 + ky) * 2;
        float ar = 0.f, ai = 0.f;
        #pragma unroll 8
        for (int i = 0; i < 32; ++i) {
            size_t xo = xbase + (size_t)i * 576;
            float xr = X[xo]     + X[SZ_X + xo];
            float xi = X[xo + 1] + X[SZ_X + xo + 1];
            float wrr = wr[wbase + (size_t)i * 4608];
            float wii = wi[wbase + (size_t)i * 4608];
            ar += xr * wrr - xi * wii;
            ai += xr * wii + xi * wrr;
        }
        Os[2 * tid] = ar; Os[2 * tid + 1] = ai;
    }
    __syncthreads();
    int row = tid & 31, ky = tid >> 5;
    int x = x0 + row;
    float zr = 0.f, zi = 0.f;
    #pragma unroll
    for (int k = 0; k < NK; ++k) {
        float orr = Os[(k * 12 + ky) * 2], oii = Os[(k * 12 + ky) * 2 + 1];
        float cc = tw[(k * Hp + x) * 2], ss = tw[(k * Hp + x) * 2 + 1];
        zr += orr * cc - oii * ss;        // e^{+i t}
        zi += orr * ss + oii * cc;
    }
    size_t o = ((((size_t)b * Hp + x) * C + c) * KY + ky) * 2;
    Z[o] = zr; Z[o + 1] = zi;
}

// conv partial for one 12-y chunk (constant-indexed acc only — r8 lesson)
__device__ __forceinline__ void conv12(const float* __restrict__ hs,
                                       const float* __restrict__ cws,
                                       int o, int ybase, float bias, float* acc) {
    #pragma unroll
    for (int j = 0; j < 12; ++j) acc[j] = bias;
    #pragma unroll 8
    for (int c = 0; c < 32; ++c) {
        float w = cws[o * 33 + c];
        const float* hr = &hs[c * 288 + ybase];
        float4 h0 = *(const float4*)&hr[0];
        float4 h1 = *(const float4*)&hr[4];
        float4 h2 = *(const float4*)&hr[8];
        acc[0] += h0.x * w; acc[1] += h0.y * w; acc[2]  += h0.z * w; acc[3]  += h0.w * w;
        acc[4] += h1.x * w; acc[5] += h1.y * w; acc[6]  += h1.z * w; acc[7]  += h1.w * w;
        acc[8] += h2.x * w; acc[9] += h2.y * w; acc[10] += h2.z * w; acc[11] += h2.w * w;
    }
    SCHED_FENCE();
}

// inverse-DFT-y only (no gelu, no fDFT) for one chunk — layer 3 epilogue
__device__ __forceinline__ void epi12_plain(const float* __restrict__ twy, int ybase,
                                            float* acc, const float* zr, const float* zi) {
    #pragma unroll
    for (int j = 0; j < 12; ++j) {
        const float* tg = twy + (ybase + j) * 24;
        float tc[24];
        #pragma unroll
        for (int q = 0; q < 6; ++q) *(float4*)&tc[4 * q] = *(const float4*)&tg[4 * q];
        float sp = zr[0] * tc[0] - zi[0] * tc[1];
        #pragma unroll
        for (int k = 1; k < 12; ++k) sp += 2.f * (zr[k] * tc[2*k] - zi[k] * tc[2*k+1]);
        acc[j] += sp * (1.0f / 82944.0f);
        if (j & 1) SCHED_FENCE();
    }
}

// fused: 1x1 conv + inverse DFT-y + bias + gelu (in place) + forward DFT-y -> Y.
// r12 kernel (async staging), used for layers 0..2 (always gelu+wy).
__global__ __launch_bounds__(256, 1) void k_conv(
        float* __restrict__ h, const float* __restrict__ Z,
        const float* __restrict__ cw, const float* __restrict__ cb,
        const float* __restrict__ twT, float* __restrict__ Y, int l) {
    __shared__ __align__(16) float hs[9216];        // [c][y] stride 288; YP alias
    __shared__ __align__(16) float twy[6912];       // [y][k][2]
    __shared__ __align__(16) float cws[32 * 33];
    __shared__ float cbs[32];
    int x = blockIdx.x, b = blockIdx.y, tid = threadIdx.x;
    size_t rowbase = (size_t)b * 2654208 + (size_t)x * 288;
    const float* hb = h + rowbase;
#if HAS_ASYNC
    #pragma unroll 1
    for (int r = 0; r < 9; ++r) {
        int i = r * 256 + tid;
        ASYNC_CP16(&hs[4 * i], hb + (size_t)(i / 72) * 82944 + (i % 72) * 4);
    }
    #pragma unroll 1
    for (int i = tid; i < 1728; i += 256)
        ASYNC_CP16(&twy[4 * i], twT + 4 * i);
#else
    for (int i = tid; i < 2304; i += 256)
        *(float4*)&hs[4 * i] = *(const float4*)&hb[(size_t)(i / 72) * 82944 + (i % 72) * 4];
    for (int i = tid; i < 1728; i += 256)
        *(float4*)&twy[4 * i] = *(const float4*)&twT[4 * i];
#endif
    for (int i = tid; i < 32 * 32; i += 256)
        cws[(i >> 5) * 33 + (i & 31)] = cw[l * 1024 + i];
    if (tid < 32) cbs[tid] = cb[l * 32 + tid];
    int o = tid & 31, g = tid >> 5;
    const float* Zr = Z + ((size_t)(b * 288 + x) * 32 + o) * 24;
    float zr[12], zi[12];
    #pragma unroll
    for (int q = 0; q < 6; ++q) {
        float4 zv = *(const float4*)&Zr[4 * q];
        zr[2*q] = zv.x; zi[2*q] = zv.y; zr[2*q+1] = zv.z; zi[2*q+1] = zv.w;
    }
    __syncthreads();
    float bias = cbs[o];
    float pr[12], pi[12];
    #pragma unroll
    for (int k = 0; k < 12; ++k) { pr[k] = 0.f; pi[k] = 0.f; }
    #pragma unroll 1
    for (int c3 = 0; c3 < 3; ++c3) {
        int ybase = g * 36 + c3 * 12;
        float acc[12];
        conv12(hs, cws, o, ybase, bias, acc);
        #pragma unroll
        for (int jp = 0; jp < 6; ++jp) {
            #pragma unroll
            for (int u = 0; u < 2; ++u) {
                int j = jp * 2 + u;
                int y = ybase + j;
                float tc[24];
                #pragma unroll
                for (int q = 0; q < 6; ++q) *(float4*)&tc[4 * q] = *(const float4*)&twy[y * 24 + 4 * q];
                float sp = zr[0] * tc[0] - zi[0] * tc[1];
                #pragma unroll
                for (int k = 1; k < 12; ++k) sp += 2.f * (zr[k] * tc[2*k] - zi[k] * tc[2*k+1]);
                float val = acc[j] + sp * (1.0f / 82944.0f);
                val = GELU(val);
                acc[j] = val;
                #pragma unroll
                for (int k = 0; k < 12; ++k) { pr[k] += val * tc[2*k]; pi[k] -= val * tc[2*k+1]; }
            }
            SCHED_FENCE();
        }
        float* hw = h + rowbase + (size_t)o * 82944 + ybase;
        #pragma unroll
        for (int q = 0; q < 3; ++q)
            *(float4*)&hw[4 * q] = make_float4(acc[4*q], acc[4*q+1], acc[4*q+2], acc[4*q+3]);
        SCHED_FENCE();
    }
    #pragma unroll
    for (int k = 0; k < 12; ++k) { pr[k] += __shfl_xor(pr[k], 32); pi[k] += __shfl_xor(pi[k], 32); }
    __syncthreads();
    float* YP = hs;
    if ((tid & 32) == 0) {
        float* dst = YP + ((tid >> 6) * 32 + o) * 24;
        #pragma unroll
        for (int k = 0; k < 12; ++k) { dst[2 * k] = pr[k]; dst[2 * k + 1] = pi[k]; }
    }
    __syncthreads();
    for (int i = tid; i < 768; i += 256) {
        float s = YP[i] + YP[768 + i] + YP[1536 + i] + YP[2304 + i];
        Y[((size_t)(b * 32 + i / 24) * 288 + x) * 24 + (i % 24)] = s;
    }
}

// layer-3 conv + inverse DFT-y (no gelu) fused directly with the output MLP:
// conv results go to LDS (hs, overwritten after all conv reads), then each
// thread runs the 32->gelu(128)->2 MLP for one pixel and writes tmp.
// Deletes the k_mlp dispatch, l=3's 74 MB h-store and k_mlp's 67 MB h-load.
__global__ __launch_bounds__(256, 1) void k_convmlp(
        const float* __restrict__ h, const float* __restrict__ Z,
        const float* __restrict__ cw, const float* __restrict__ cb,
        const float* __restrict__ twT,
        const float* __restrict__ mw1, const float* __restrict__ mb1,
        const float* __restrict__ mw2, const float* __restrict__ mb2,
        float* __restrict__ tmp) {
    __shared__ __align__(16) float hs[9216];        // [c][y] stride 288; reused for MLP input
    __shared__ __align__(16) float twy[6912];
    __shared__ __align__(16) float cws[32 * 33];
    __shared__ float cbs[32];
    int x = blockIdx.x, b = blockIdx.y, tid = threadIdx.x;
    size_t rowbase = (size_t)b * 2654208 + (size_t)x * 288;
    const float* hb = h + rowbase;
#if HAS_ASYNC
    #pragma unroll 1
    for (int r = 0; r < 9; ++r) {
        int i = r * 256 + tid;
        ASYNC_CP16(&hs[4 * i], hb + (size_t)(i / 72) * 82944 + (i % 72) * 4);
    }
    #pragma unroll 1
    for (int i = tid; i < 1728; i += 256)
        ASYNC_CP16(&twy[4 * i], twT + 4 * i);
#else
    for (int i = tid; i < 2304; i += 256)
        *(float4*)&hs[4 * i] = *(const float4*)&hb[(size_t)(i / 72) * 82944 + (i % 72) * 4];
    for (int i = tid; i < 1728; i += 256)
        *(float4*)&twy[4 * i] = *(const float4*)&twT[4 * i];
#endif
    for (int i = tid; i < 32 * 32; i += 256)
        cws[(i >> 5) * 33 + (i & 31)] = cw[3 * 1024 + i];
    if (tid < 32) cbs[tid] = cb[3 * 32 + tid];
    int o = tid & 31, g = tid >> 5;
    const float* Zr = Z + ((size_t)(b * 288 + x) * 32 + o) * 24;
    float zr[12], zi[12];
    #pragma unroll
    for (int q = 0; q < 6; ++q) {
        float4 zv = *(const float4*)&Zr[4 * q];
        zr[2*q] = zv.x; zi[2*q] = zv.y; zr[2*q+1] = zv.z; zi[2*q+1] = zv.w;
    }
    __syncthreads();
    float bias = cbs[o];
    // all conv reads first (hs is overwritten below) — three NAMED acc arrays,
    // constant-indexed only (r8 lesson)
    float a0[12], a1[12], a2[12];
    conv12(hs, cws, o, g * 36,      bias, a0);
    conv12(hs, cws, o, g * 36 + 12, bias, a1);
    conv12(hs, cws, o, g * 36 + 24, bias, a2);
    epi12_plain(twy, g * 36,      a0, zr, zi);
    epi12_plain(twy, g * 36 + 12, a1, zr, zi);
    epi12_plain(twy, g * 36 + 24, a2, zr, zi);
    __syncthreads();                                 // everyone done reading hs
    {
        float* hw = hs + o * 288 + g * 36;
        #pragma unroll
        for (int q = 0; q < 3; ++q) {
            *(float4*)&hw[4 * q]      = make_float4(a0[4*q], a0[4*q+1], a0[4*q+2], a0[4*q+3]);
            *(float4*)&hw[12 + 4 * q] = make_float4(a1[4*q], a1[4*q+1], a1[4*q+2], a1[4*q+3]);
            *(float4*)&hw[24 + 4 * q] = make_float4(a2[4*q], a2[4*q+1], a2[4*q+2], a2[4*q+3]);
        }
    }
    __syncthreads();
    // MLP phase: thread = pixel y (0..255)
    float hc[32];
    #pragma unroll
    for (int c = 0; c < 32; ++c) hc[c] = hs[c * 288 + tid];
    float o0 = 0.f, o1 = 0.f;
    #pragma unroll 4
    for (int f = 0; f < 128; ++f) {
        float a = mb1[f];
        #pragma unroll
        for (int c = 0; c < 32; ++c) a += hc[c] * mw1[f * 32 + c];
        float gl = GELU(a);
        o0 += gl * mw2[f]; o1 += gl * mw2[128 + f];
    }
    size_t p = (size_t)b * 65536 + x * 256 + tid;
    *(float2*)&tmp[p * 2] = make_float2(o0 + mb2[0], o1 + mb2[1]);
}

// out[b][j][d] = tmp[b][v2d[j]][d]
__global__ void k_scatter(const float* __restrict__ tmp, const int* __restrict__ v2d,
                          float* __restrict__ out) {
    int id = blockIdx.x * 256 + threadIdx.x;
    int b = id >> 16; int j = id & 65535;
    int p = v2d[j];
    const float2 v = *(const float2*)(tmp + ((size_t)(b << 16) + p) * 2);
    *(float2*)(out + (size_t)id * 2) = v;
}

extern "C" void kernel_launch(void* const* d_in, const int* in_sizes, int n_in,
                              void* d_out, int out_size, void* d_ws, size_t ws_size,
                              hipStream_t stream) {
    const float* xin   = (const float*)d_in[0];
    const int*   d2v   = (const int*)  d_in[1];
    const int*   v2d   = (const int*)  d_in[2];
    const float* fc0w  = (const float*)d_in[3];
    const float* fc0b  = (const float*)d_in[4];
    const float* w1r   = (const float*)d_in[5];
    const float* w1i   = (const float*)d_in[6];
    const float* w2r   = (const float*)d_in[7];
    const float* w2i   = (const float*)d_in[8];
    const float* cw    = (const float*)d_in[9];
    const float* cb    = (const float*)d_in[10];
    const float* mw1   = (const float*)d_in[11];
    const float* mb1   = (const float*)d_in[12];
    const float* mw2   = (const float*)d_in[13];
    const float* mb2   = (const float*)d_in[14];

    float* ws  = (float*)d_ws;
    float* TW  = ws + OFF_TW;
    float* TWT = ws + OFF_TWT;
    float* H   = ws + OFF_H;
    float* Y   = ws + OFF_Y;
    float* X   = ws + OFF_X;
    float* Z   = ws + OFF_Z;
    float* T   = ws + OFF_T;

    k_tw<<<(NK * Hp + 255) / 256, 256, 0, stream>>>(TW, TWT);
    k_embed<<<dim3(Hp, Bn), 256, 0, stream>>>(xin, d2v, fc0w, fc0b, TWT, H, Y);

    for (int l = 0; l < 4; ++l) {
        k_dftx<<<dim3(32, Bn, 2), 288, 0, stream>>>(Y, TW, X);
        k_specidft<<<dim3(9, 32, Bn), 384, 0, stream>>>(X, w1r, w1i, w2r, w2i, TW, Z, l);
        if (l != 3)
            k_conv<<<dim3(Hp, Bn), 256, 0, stream>>>(H, Z, cw, cb, TWT, Y, l);
        else
            k_convmlp<<<dim3(S, Bn), 256, 0, stream>>>(H, Z, cw, cb, TWT, mw1, mb1, mw2, mb2, T);
    }

    k_scatter<<<(Bn * S * S) / 256, 256, 0, stream>>>(T, v2d, (float*)d_out);
}

// Round 14
// 1032.665 us; speedup vs baseline: 1.0131x; 1.0131x over previous
//
#include <hip/hip_runtime.h>
#include <math.h>

#define S    256
#define Hp   288
#define C    32
#define KY   12
#define NK   24
#define Bn   8
#define PI_D 3.14159265358979323846264338327950288

// workspace offsets (in floats)
#define SZ_TW  (NK*Hp*2)                // 13824  [k][x] layout, k<24
#define OFF_TW 0
#define OFF_TWT (OFF_TW + SZ_TW)
#define SZ_TWT (Hp*KY*2)                // 6912   [y][k][2] transposed, k<12
#define OFF_H  (OFF_TWT + SZ_TWT)
#define SZ_H   (Bn*C*Hp*Hp)             // 21233664
#define OFF_Y  (OFF_H + SZ_H)
#define SZ_Y   (Bn*C*Hp*KY*2)           // 1769472
#define OFF_X  (OFF_Y + SZ_Y)
#define SZ_X   (Bn*C*NK*KY*2)           // 147456 (one half-partial)
#define OFF_Z  (OFF_X + 2*SZ_X)
#define SZ_Z   (Bn*Hp*C*KY*2)           // 1769472
#define OFF_T  (OFF_Z + SZ_Z)
#define SZ_T   (Bn*S*S*2)               // 1048576

#define GELU(v) (0.5f*(v)*(1.0f+erff((v)*0.70710678118654752f)))
#define SCHED_FENCE() __builtin_amdgcn_sched_barrier(0)

#if __has_builtin(__builtin_amdgcn_global_load_lds)
#define HAS_ASYNC 1
#define ASYNC_CP16(dst, src) \
    __builtin_amdgcn_global_load_lds((const __attribute__((address_space(1))) void*)(src), \
                                     (__attribute__((address_space(3))) void*)(dst), 16, 0, 0)
#else
#define HAS_ASYNC 0
#endif

// twiddle tables: tw[k][x] (k<24, both signs) and transposed twT[x][k][2] (k<12)
__global__ void k_tw(float* __restrict__ tw, float* __restrict__ twT) {
    int i = blockIdx.x * 256 + threadIdx.x;
    if (i >= NK * Hp) return;
    int k = i / Hp, xx = i % Hp;
    int f = (k < KY) ? k : (k + 264);
    int m = (f * xx) % Hp;                        // exact integer phase reduction
    double th = (2.0 * PI_D * (double)m) / (double)Hp;
    float c = (float)cos(th), s = (float)sin(th);
    tw[2 * i] = c; tw[2 * i + 1] = s;
    if (k < KY) { twT[xx * 24 + 2 * k] = c; twT[xx * 24 + 2 * k + 1] = s; }
}

// embed main body, templated on quarter Q (wave-uniform: Q = tid>>6).
template<int Q>
__device__ __forceinline__ void embed_body(
        const float* __restrict__ xs, const float* __restrict__ twq,
        float* __restrict__ h, size_t rowbase, int o, int g,
        float w0, float w1, float w2, float bb, float gx,
        float* pr, float* pi) {
    #pragma unroll 1
    for (int c3 = 0; c3 < 3; ++c3) {
        int ybase = g * 36 + c3 * 12;
        int rowq  = (g & 1) * 36 + c3 * 12;
        float acc[12];
        #pragma unroll
        for (int j = 0; j < 12; ++j) {
            int y = ybase + j;
            acc[j] = (y < S) ? (w0 * xs[y < S ? y : 0] + w1 * gx + w2 * (y * (1.0f / 255.0f)) + bb) : 0.f;
        }
        float* hw = h + rowbase + (size_t)o * 82944 + ybase;
        #pragma unroll
        for (int q = 0; q < 3; ++q)
            *(float4*)&hw[4 * q] = make_float4(acc[4*q], acc[4*q+1], acc[4*q+2], acc[4*q+3]);
        SCHED_FENCE();
        #pragma unroll
        for (int jp = 0; jp < 6; ++jp) {
            #pragma unroll
            for (int u = 0; u < 2; ++u) {
                int j = jp * 2 + u;
                const float* tg = twq + (rowq + j) * 24;
                float tc[24];
                #pragma unroll
                for (int q = 0; q < 6; ++q) *(float4*)&tc[4 * q] = *(const float4*)&tg[4 * q];
                float v = acc[j];
                pr[0] += v;                          // k=0: (1,0) in all quarters
                #pragma unroll
                for (int k = 1; k < 12; ++k) {
                    const int e = (k * Q) & 3;
                    float c = tc[2 * k], s = tc[2 * k + 1];
                    if      (e == 0) { pr[k] += v * c; pi[k] -= v * s; }
                    else if (e == 1) { pr[k] -= v * s; pi[k] -= v * c; }
                    else if (e == 2) { pr[k] -= v * c; pi[k] += v * s; }
                    else             { pr[k] += v * s; pi[k] += v * c; }
                }
            }
            SCHED_FENCE();
        }
    }
}

// gather + grid + fc0 + pad -> h row, fused forward DFT-y -> Y. (r11, best)
__global__ __launch_bounds__(256, 1) void k_embed(
        const float* __restrict__ xin, const int* __restrict__ d2v,
        const float* __restrict__ fw, const float* __restrict__ fb,
        const float* __restrict__ twT, float* __restrict__ h, float* __restrict__ Y) {
    __shared__ __align__(16) float xs[256];
    __shared__ __align__(16) float twq[1728];       // quarter table, rows y<72
    __shared__ __align__(16) float YP[3072];
    int x = blockIdx.x, b = blockIdx.y, tid = threadIdx.x;
    size_t rowbase = (size_t)b * 2654208 + (size_t)x * 288;
    if (x >= S) {                                   // pad rows: h=0, Y=0
        for (int i = tid; i < 32 * 72; i += 256) {
            int c = i / 72, q = i % 72;
            *(float4*)&h[rowbase + (size_t)c * 82944 + q * 4] = make_float4(0, 0, 0, 0);
        }
        for (int i = tid; i < 768; i += 256)
            Y[((size_t)(b * 32 + i / 24) * 288 + x) * 24 + (i % 24)] = 0.f;
        return;
    }
    for (int i = tid; i < 432; i += 256)
        *(float4*)&twq[4 * i] = *(const float4*)&twT[4 * i];
    xs[tid] = xin[b * 65536 + d2v[x * 256 + tid]];
    int o = tid & 31, g = tid >> 5;
    float w0 = fw[o * 3], w1 = fw[o * 3 + 1], w2 = fw[o * 3 + 2], bb = fb[o];
    float gx = x * (1.0f / 255.0f);
    __syncthreads();
    float pr[12], pi[12];
    #pragma unroll
    for (int k = 0; k < 12; ++k) { pr[k] = 0.f; pi[k] = 0.f; }
    switch (tid >> 6) {                              // quarter = wave id (uniform)
        case 0: embed_body<0>(xs, twq, h, rowbase, o, g, w0, w1, w2, bb, gx, pr, pi); break;
        case 1: embed_body<1>(xs, twq, h, rowbase, o, g, w0, w1, w2, bb, gx, pr, pi); break;
        case 2: embed_body<2>(xs, twq, h, rowbase, o, g, w0, w1, w2, bb, gx, pr, pi); break;
        default: embed_body<3>(xs, twq, h, rowbase, o, g, w0, w1, w2, bb, gx, pr, pi); break;
    }
    #pragma unroll
    for (int k = 0; k < 12; ++k) { pr[k] += __shfl_xor(pr[k], 32); pi[k] += __shfl_xor(pi[k], 32); }
    if ((tid & 32) == 0) {
        float* dst = YP + ((tid >> 6) * 32 + o) * 24;
        #pragma unroll
        for (int k = 0; k < 12; ++k) { dst[2 * k] = pr[k]; dst[2 * k + 1] = pi[k]; }
    }
    __syncthreads();
    for (int i = tid; i < 768; i += 256) {
        float s = YP[i] + YP[768 + i] + YP[1536 + i] + YP[2304 + i];
        Y[((size_t)(b * 32 + i / 24) * 288 + x) * 24 + (i % 24)] = s;
    }
}

// forward DFT along x, split into 2 x-half partials. X[half][b][c][k][ky]
__global__ __launch_bounds__(288) void k_dftx(const float* __restrict__ Y,
                                              const float* __restrict__ tw,
                                              float* __restrict__ X) {
    __shared__ __align__(16) float Ys[144 * 24];
    int c = blockIdx.x, b = blockIdx.y, half = blockIdx.z, tid = threadIdx.x;
    const float* Yb = Y + (size_t)(b * 32 + c) * 6912 + half * 3456;
    for (int i = tid; i < 864; i += 288)
        *(float4*)&Ys[4 * i] = *(const float4*)&Yb[4 * i];
    __syncthreads();
    int k = tid / 12, ky = tid % 12;
    const float* twk = tw + k * 576 + half * 288;
    float xr = 0.f, xi = 0.f;
    #pragma unroll 4
    for (int xx = 0; xx < 144; ++xx) {
        float yr = Ys[xx * 24 + 2 * ky], yi = Ys[xx * 24 + 2 * ky + 1];
        float cc = twk[2 * xx], ss = twk[2 * xx + 1];
        xr += yr * cc + yi * ss;      // e^{-i t}
        xi += yi * cc - yr * ss;
    }
    size_t oo = (size_t)half * SZ_X + ((size_t)(b * 32 + c) * 288 + tid) * 2;
    X[oo] = xr; X[oo + 1] = xi;
}

// fused spec + inverse-DFT-x (r12 kernel, kept).
__global__ __launch_bounds__(384) void k_specidft(
        const float* __restrict__ X,
        const float* __restrict__ w1r, const float* __restrict__ w1i,
        const float* __restrict__ w2r, const float* __restrict__ w2i,
        const float* __restrict__ tw, float* __restrict__ Z, int l) {
    __shared__ __align__(16) float Os[576];
    int x0 = blockIdx.x * 32, c = blockIdx.y, b = blockIdx.z, tid = threadIdx.x;
    if (tid < 288) {
        int k = tid / 12, ky = tid % 12;
        int kk = (k < KY) ? k : (k - KY);
        const float* wr = (k < KY) ? w1r : w2r;
        const float* wi = (k < KY) ? w1i : w2i;
        size_t wbase = (size_t)l * 147456 + (size_t)c * 144 + kk * 12 + ky;
        size_t xbase = (size_t)b * 18432 + (k * 12 + ky) * 2;
        float ar = 0.f, ai = 0.f;
        #pragma unroll 8
        for (int i = 0; i < 32; ++i) {
            size_t xo = xbase + (size_t)i * 576;
            float xr = X[xo]     + X[SZ_X + xo];
            float xi = X[xo + 1] + X[SZ_X + xo + 1];
            float wrr = wr[wbase + (size_t)i * 4608];
            float wii = wi[wbase + (size_t)i * 4608];
            ar += xr * wrr - xi * wii;
            ai += xr * wii + xi * wrr;
        }
        Os[2 * tid] = ar; Os[2 * tid + 1] = ai;
    }
    __syncthreads();
    int row = tid & 31, ky = tid >> 5;
    int x = x0 + row;
    float zr = 0.f, zi = 0.f;
    #pragma unroll
    for (int k = 0; k < NK; ++k) {
        float orr = Os[(k * 12 + ky) * 2], oii = Os[(k * 12 + ky) * 2 + 1];
        float cc = tw[(k * Hp + x) * 2], ss = tw[(k * Hp + x) * 2 + 1];
        zr += orr * cc - oii * ss;        // e^{+i t}
        zi += orr * ss + oii * cc;
    }
    size_t o = ((((size_t)b * Hp + x) * C + c) * KY + ky) * 2;
    Z[o] = zr; Z[o + 1] = zi;
}

// conv partial for one 12-y chunk (constant-indexed acc only — r8 lesson)
__device__ __forceinline__ void conv12(const float* __restrict__ hs,
                                       const float* __restrict__ cws,
                                       int o, int ybase, float bias, float* acc) {
    #pragma unroll
    for (int j = 0; j < 12; ++j) acc[j] = bias;
    #pragma unroll 8
    for (int c = 0; c < 32; ++c) {
        float w = cws[o * 33 + c];
        const float* hr = &hs[c * 288 + ybase];
        float4 h0 = *(const float4*)&hr[0];
        float4 h1 = *(const float4*)&hr[4];
        float4 h2 = *(const float4*)&hr[8];
        acc[0] += h0.x * w; acc[1] += h0.y * w; acc[2]  += h0.z * w; acc[3]  += h0.w * w;
        acc[4] += h1.x * w; acc[5] += h1.y * w; acc[6]  += h1.z * w; acc[7]  += h1.w * w;
        acc[8] += h2.x * w; acc[9] += h2.y * w; acc[10] += h2.z * w; acc[11] += h2.w * w;
    }
    SCHED_FENCE();
}

// inverse-DFT-y only (no gelu, no fDFT) for one chunk — layer 3 epilogue
__device__ __forceinline__ void epi12_plain(const float* __restrict__ twy, int ybase,
                                            float* acc, const float* zr, const float* zi) {
    #pragma unroll
    for (int j = 0; j < 12; ++j) {
        const float* tg = twy + (ybase + j) * 24;
        float tc[24];
        #pragma unroll
        for (int q = 0; q < 6; ++q) *(float4*)&tc[4 * q] = *(const float4*)&tg[4 * q];
        float sp = zr[0] * tc[0] - zi[0] * tc[1];
        #pragma unroll
        for (int k = 1; k < 12; ++k) sp += 2.f * (zr[k] * tc[2*k] - zi[k] * tc[2*k+1]);
        acc[j] += sp * (1.0f / 82944.0f);
        if (j & 1) SCHED_FENCE();
    }
}

// fused: 1x1 conv + inverse DFT-y + bias + gelu (in place) + forward DFT-y -> Y.
// r12 kernel (async staging), used for layers 0..2 (always gelu+wy).
__global__ __launch_bounds__(256, 1) void k_conv(
        float* __restrict__ h, const float* __restrict__ Z,
        const float* __restrict__ cw, const float* __restrict__ cb,
        const float* __restrict__ twT, float* __restrict__ Y, int l) {
    __shared__ __align__(16) float hs[9216];        // [c][y] stride 288; YP alias
    __shared__ __align__(16) float twy[6912];       // [y][k][2]
    __shared__ __align__(16) float cws[32 * 33];
    __shared__ float cbs[32];
    int x = blockIdx.x, b = blockIdx.y, tid = threadIdx.x;
    size_t rowbase = (size_t)b * 2654208 + (size_t)x * 288;
    const float* hb = h + rowbase;
#if HAS_ASYNC
    #pragma unroll 1
    for (int r = 0; r < 9; ++r) {
        int i = r * 256 + tid;
        ASYNC_CP16(&hs[4 * i], hb + (size_t)(i / 72) * 82944 + (i % 72) * 4);
    }
    #pragma unroll 1
    for (int i = tid; i < 1728; i += 256)
        ASYNC_CP16(&twy[4 * i], twT + 4 * i);
#else
    for (int i = tid; i < 2304; i += 256)
        *(float4*)&hs[4 * i] = *(const float4*)&hb[(size_t)(i / 72) * 82944 + (i % 72) * 4];
    for (int i = tid; i < 1728; i += 256)
        *(float4*)&twy[4 * i] = *(const float4*)&twT[4 * i];
#endif
    for (int i = tid; i < 32 * 32; i += 256)
        cws[(i >> 5) * 33 + (i & 31)] = cw[l * 1024 + i];
    if (tid < 32) cbs[tid] = cb[l * 32 + tid];
    int o = tid & 31, g = tid >> 5;
    const float* Zr = Z + ((size_t)(b * 288 + x) * 32 + o) * 24;
    float zr[12], zi[12];
    #pragma unroll
    for (int q = 0; q < 6; ++q) {
        float4 zv = *(const float4*)&Zr[4 * q];
        zr[2*q] = zv.x; zi[2*q] = zv.y; zr[2*q+1] = zv.z; zi[2*q+1] = zv.w;
    }
    __syncthreads();
    float bias = cbs[o];
    float pr[12], pi[12];
    #pragma unroll
    for (int k = 0; k < 12; ++k) { pr[k] = 0.f; pi[k] = 0.f; }
    #pragma unroll 1
    for (int c3 = 0; c3 < 3; ++c3) {
        int ybase = g * 36 + c3 * 12;
        float acc[12];
        conv12(hs, cws, o, ybase, bias, acc);
        #pragma unroll
        for (int jp = 0; jp < 6; ++jp) {
            #pragma unroll
            for (int u = 0; u < 2; ++u) {
                int j = jp * 2 + u;
                int y = ybase + j;
                float tc[24];
                #pragma unroll
                for (int q = 0; q < 6; ++q) *(float4*)&tc[4 * q] = *(const float4*)&twy[y * 24 + 4 * q];
                float sp = zr[0] * tc[0] - zi[0] * tc[1];
                #pragma unroll
                for (int k = 1; k < 12; ++k) sp += 2.f * (zr[k] * tc[2*k] - zi[k] * tc[2*k+1]);
                float val = acc[j] + sp * (1.0f / 82944.0f);
                val = GELU(val);
                acc[j] = val;
                #pragma unroll
                for (int k = 0; k < 12; ++k) { pr[k] += val * tc[2*k]; pi[k] -= val * tc[2*k+1]; }
            }
            SCHED_FENCE();
        }
        float* hw = h + rowbase + (size_t)o * 82944 + ybase;
        #pragma unroll
        for (int q = 0; q < 3; ++q)
            *(float4*)&hw[4 * q] = make_float4(acc[4*q], acc[4*q+1], acc[4*q+2], acc[4*q+3]);
        SCHED_FENCE();
    }
    #pragma unroll
    for (int k = 0; k < 12; ++k) { pr[k] += __shfl_xor(pr[k], 32); pi[k] += __shfl_xor(pi[k], 32); }
    __syncthreads();
    float* YP = hs;
    if ((tid & 32) == 0) {
        float* dst = YP + ((tid >> 6) * 32 + o) * 24;
        #pragma unroll
        for (int k = 0; k < 12; ++k) { dst[2 * k] = pr[k]; dst[2 * k + 1] = pi[k]; }
    }
    __syncthreads();
    for (int i = tid; i < 768; i += 256) {
        float s = YP[i] + YP[768 + i] + YP[1536 + i] + YP[2304 + i];
        Y[((size_t)(b * 32 + i / 24) * 288 + x) * 24 + (i % 24)] = s;
    }
}

// layer-3 conv + inverse DFT-y (no gelu) fused with the output MLP.
// FIX vs r13: the conv->MLP handoff buffer is [y][c] stride 33 (bank-conflict-
// free both for the o-lane writes and the y-lane reads); r13's hs[o*288+y]
// write had stride 288 ≡ 0 (mod 32 banks) -> 32-way conflicts (4.1M counted).
// ms aliases the dead hs+twy region (all reads complete before the sync).
__global__ __launch_bounds__(256, 1) void k_convmlp(
        const float* __restrict__ h, const float* __restrict__ Z,
        const float* __restrict__ cw, const float* __restrict__ cb,
        const float* __restrict__ twT,
        const float* __restrict__ mw1, const float* __restrict__ mb1,
        const float* __restrict__ mw2, const float* __restrict__ mb2,
        float* __restrict__ tmp) {
    __shared__ __align__(16) float smem[16128];     // [0,9216) hs | [9216,16128) twy
    __shared__ __align__(16) float cws[32 * 33];
    __shared__ float cbs[32];
    float* hs  = smem;
    float* twy = smem + 9216;
    int x = blockIdx.x, b = blockIdx.y, tid = threadIdx.x;
    size_t rowbase = (size_t)b * 2654208 + (size_t)x * 288;
    const float* hb = h + rowbase;
#if HAS_ASYNC
    #pragma unroll 1
    for (int r = 0; r < 9; ++r) {
        int i = r * 256 + tid;
        ASYNC_CP16(&hs[4 * i], hb + (size_t)(i / 72) * 82944 + (i % 72) * 4);
    }
    #pragma unroll 1
    for (int i = tid; i < 1728; i += 256)
        ASYNC_CP16(&twy[4 * i], twT + 4 * i);
#else
    for (int i = tid; i < 2304; i += 256)
        *(float4*)&hs[4 * i] = *(const float4*)&hb[(size_t)(i / 72) * 82944 + (i % 72) * 4];
    for (int i = tid; i < 1728; i += 256)
        *(float4*)&twy[4 * i] = *(const float4*)&twT[4 * i];
#endif
    for (int i = tid; i < 32 * 32; i += 256)
        cws[(i >> 5) * 33 + (i & 31)] = cw[3 * 1024 + i];
    if (tid < 32) cbs[tid] = cb[3 * 32 + tid];
    int o = tid & 31, g = tid >> 5;
    const float* Zr = Z + ((size_t)(b * 288 + x) * 32 + o) * 24;
    float zr[12], zi[12];
    #pragma unroll
    for (int q = 0; q < 6; ++q) {
        float4 zv = *(const float4*)&Zr[4 * q];
        zr[2*q] = zv.x; zi[2*q] = zv.y; zr[2*q+1] = zv.z; zi[2*q+1] = zv.w;
    }
    __syncthreads();
    float bias = cbs[o];
    // all conv + epilogue reads first (smem is overwritten below) — three
    // NAMED acc arrays, constant-indexed only (r8 lesson)
    float a0[12], a1[12], a2[12];
    conv12(hs, cws, o, g * 36,      bias, a0);
    conv12(hs, cws, o, g * 36 + 12, bias, a1);
    conv12(hs, cws, o, g * 36 + 24, bias, a2);
    epi12_plain(twy, g * 36,      a0, zr, zi);
    epi12_plain(twy, g * 36 + 12, a1, zr, zi);
    epi12_plain(twy, g * 36 + 24, a2, zr, zi);
    __syncthreads();                                 // everyone done reading smem
    // handoff: ms[y*33 + o] — conflict-free (consecutive banks across o-lanes)
    float* ms = smem;                                // 9504 floats < 16128
    {
        int yb = g * 36;
        #pragma unroll
        for (int j = 0; j < 12; ++j) {
            ms[(yb + j)      * 33 + o] = a0[j];
            ms[(yb + 12 + j) * 33 + o] = a1[j];
            ms[(yb + 24 + j) * 33 + o] = a2[j];
        }
    }
    __syncthreads();
    // MLP phase: thread = pixel y (0..255); reads ms[y*33+c] (bank (y+c)%32)
    float hc[32];
    #pragma unroll
    for (int c = 0; c < 32; ++c) hc[c] = ms[tid * 33 + c];
    float o0 = 0.f, o1 = 0.f;
    #pragma unroll 4
    for (int f = 0; f < 128; ++f) {
        float a = mb1[f];
        #pragma unroll
        for (int c = 0; c < 32; ++c) a += hc[c] * mw1[f * 32 + c];
        float gl = GELU(a);
        o0 += gl * mw2[f]; o1 += gl * mw2[128 + f];
    }
    size_t p = (size_t)b * 65536 + x * 256 + tid;
    *(float2*)&tmp[p * 2] = make_float2(o0 + mb2[0], o1 + mb2[1]);
}

// out[b][j][d] = tmp[b][v2d[j]][d]
__global__ void k_scatter(const float* __restrict__ tmp, const int* __restrict__ v2d,
                          float* __restrict__ out) {
    int id = blockIdx.x * 256 + threadIdx.x;
    int b = id >> 16; int j = id & 65535;
    int p = v2d[j];
    const float2 v = *(const float2*)(tmp + ((size_t)(b << 16) + p) * 2);
    *(float2*)(out + (size_t)id * 2) = v;
}

extern "C" void kernel_launch(void* const* d_in, const int* in_sizes, int n_in,
                              void* d_out, int out_size, void* d_ws, size_t ws_size,
                              hipStream_t stream) {
    const float* xin   = (const float*)d_in[0];
    const int*   d2v   = (const int*)  d_in[1];
    const int*   v2d   = (const int*)  d_in[2];
    const float* fc0w  = (const float*)d_in[3];
    const float* fc0b  = (const float*)d_in[4];
    const float* w1r   = (const float*)d_in[5];
    const float* w1i   = (const float*)d_in[6];
    const float* w2r   = (const float*)d_in[7];
    const float* w2i   = (const float*)d_in[8];
    const float* cw    = (const float*)d_in[9];
    const float* cb    = (const float*)d_in[10];
    const float* mw1   = (const float*)d_in[11];
    const float* mb1   = (const float*)d_in[12];
    const float* mw2   = (const float*)d_in[13];
    const float* mb2   = (const float*)d_in[14];

    float* ws  = (float*)d_ws;
    float* TW  = ws + OFF_TW;
    float* TWT = ws + OFF_TWT;
    float* H   = ws + OFF_H;
    float* Y   = ws + OFF_Y;
    float* X   = ws + OFF_X;
    float* Z   = ws + OFF_Z;
    float* T   = ws + OFF_T;

    k_tw<<<(NK * Hp + 255) / 256, 256, 0, stream>>>(TW, TWT);
    k_embed<<<dim3(Hp, Bn), 256, 0, stream>>>(xin, d2v, fc0w, fc0b, TWT, H, Y);

    for (int l = 0; l < 4; ++l) {
        k_dftx<<<dim3(32, Bn, 2), 288, 0, stream>>>(Y, TW, X);
        k_specidft<<<dim3(9, 32, Bn), 384, 0, stream>>>(X, w1r, w1i, w2r, w2i, TW, Z, l);
        if (l != 3)
            k_conv<<<dim3(Hp, Bn), 256, 0, stream>>>(H, Z, cw, cb, TWT, Y, l);
        else
            k_convmlp<<<dim3(S, Bn), 256, 0, stream>>>(H, Z, cw, cb, TWT, mw1, mb1, mw2, mb2, T);
    }

    k_scatter<<<(Bn * S * S) / 256, 256, 0, stream>>>(T, v2d, (float*)d_out);
}

// Round 15
// 825.998 us; speedup vs baseline: 1.2666x; 1.2502x over previous
//
#include <hip/hip_runtime.h>
#include <math.h>

#define S    256
#define Hp   288
#define C    32
#define KY   12
#define NK   24
#define Bn   8
#define PI_D 3.14159265358979323846264338327950288

// workspace offsets (in floats)
#define SZ_TW  (NK*Hp*2)                // 13824  [k][x] layout, k<24
#define OFF_TW 0
#define OFF_TWT (OFF_TW + SZ_TW)
#define SZ_TWT (Hp*KY*2)                // 6912   [y][k][2] transposed, k<12
#define OFF_H  (OFF_TWT + SZ_TWT)
#define SZ_H   (Bn*C*Hp*Hp)             // 21233664
#define OFF_Y  (OFF_H + SZ_H)
#define SZ_Y   (Bn*C*Hp*KY*2)           // 1769472
#define OFF_X  (OFF_Y + SZ_Y)
#define SZ_X   (Bn*C*NK*KY*2)           // 147456 (one half-partial)
#define OFF_Z  (OFF_X + 2*SZ_X)
#define SZ_Z   (Bn*Hp*C*KY*2)           // 1769472
#define OFF_T  (OFF_Z + SZ_Z)
#define SZ_T   (Bn*S*S*2)               // 1048576

#define GELU(v) (0.5f*(v)*(1.0f+erff((v)*0.70710678118654752f)))
#define SCHED_FENCE() __builtin_amdgcn_sched_barrier(0)

#if __has_builtin(__builtin_amdgcn_global_load_lds)
#define HAS_ASYNC 1
#define ASYNC_CP16(dst, src) \
    __builtin_amdgcn_global_load_lds((const __attribute__((address_space(1))) void*)(src), \
                                     (__attribute__((address_space(3))) void*)(dst), 16, 0, 0)
#else
#define HAS_ASYNC 0
#endif

// twiddle tables: tw[k][x] (k<24, both signs) and transposed twT[x][k][2] (k<12)
__global__ void k_tw(float* __restrict__ tw, float* __restrict__ twT) {
    int i = blockIdx.x * 256 + threadIdx.x;
    if (i >= NK * Hp) return;
    int k = i / Hp, xx = i % Hp;
    int f = (k < KY) ? k : (k + 264);
    int m = (f * xx) % Hp;                        // exact integer phase reduction
    double th = (2.0 * PI_D * (double)m) / (double)Hp;
    float c = (float)cos(th), s = (float)sin(th);
    tw[2 * i] = c; tw[2 * i + 1] = s;
    if (k < KY) { twT[xx * 24 + 2 * k] = c; twT[xx * 24 + 2 * k + 1] = s; }
}

// embed main body, templated on quarter Q (wave-uniform: Q = tid>>6).
template<int Q>
__device__ __forceinline__ void embed_body(
        const float* __restrict__ xs, const float* __restrict__ twq,
        float* __restrict__ h, size_t rowbase, int o, int g,
        float w0, float w1, float w2, float bb, float gx,
        float* pr, float* pi) {
    #pragma unroll 1
    for (int c3 = 0; c3 < 3; ++c3) {
        int ybase = g * 36 + c3 * 12;
        int rowq  = (g & 1) * 36 + c3 * 12;
        float acc[12];
        #pragma unroll
        for (int j = 0; j < 12; ++j) {
            int y = ybase + j;
            acc[j] = (y < S) ? (w0 * xs[y < S ? y : 0] + w1 * gx + w2 * (y * (1.0f / 255.0f)) + bb) : 0.f;
        }
        float* hw = h + rowbase + (size_t)o * 82944 + ybase;
        #pragma unroll
        for (int q = 0; q < 3; ++q)
            *(float4*)&hw[4 * q] = make_float4(acc[4*q], acc[4*q+1], acc[4*q+2], acc[4*q+3]);
        SCHED_FENCE();
        #pragma unroll
        for (int jp = 0; jp < 6; ++jp) {
            #pragma unroll
            for (int u = 0; u < 2; ++u) {
                int j = jp * 2 + u;
                const float* tg = twq + (rowq + j) * 24;
                float tc[24];
                #pragma unroll
                for (int q = 0; q < 6; ++q) *(float4*)&tc[4 * q] = *(const float4*)&tg[4 * q];
                float v = acc[j];
                pr[0] += v;                          // k=0: (1,0) in all quarters
                #pragma unroll
                for (int k = 1; k < 12; ++k) {
                    const int e = (k * Q) & 3;
                    float c = tc[2 * k], s = tc[2 * k + 1];
                    if      (e == 0) { pr[k] += v * c; pi[k] -= v * s; }
                    else if (e == 1) { pr[k] -= v * s; pi[k] -= v * c; }
                    else if (e == 2) { pr[k] -= v * c; pi[k] += v * s; }
                    else             { pr[k] += v * s; pi[k] += v * c; }
                }
            }
            SCHED_FENCE();
        }
    }
}

// gather + grid + fc0 + pad -> h row, fused forward DFT-y -> Y. (r11, best)
__global__ __launch_bounds__(256, 1) void k_embed(
        const float* __restrict__ xin, const int* __restrict__ d2v,
        const float* __restrict__ fw, const float* __restrict__ fb,
        const float* __restrict__ twT, float* __restrict__ h, float* __restrict__ Y) {
    __shared__ __align__(16) float xs[256];
    __shared__ __align__(16) float twq[1728];       // quarter table, rows y<72
    __shared__ __align__(16) float YP[3072];
    int x = blockIdx.x, b = blockIdx.y, tid = threadIdx.x;
    size_t rowbase = (size_t)b * 2654208 + (size_t)x * 288;
    if (x >= S) {                                   // pad rows: h=0, Y=0
        for (int i = tid; i < 32 * 72; i += 256) {
            int c = i / 72, q = i % 72;
            *(float4*)&h[rowbase + (size_t)c * 82944 + q * 4] = make_float4(0, 0, 0, 0);
        }
        for (int i = tid; i < 768; i += 256)
            Y[((size_t)(b * 32 + i / 24) * 288 + x) * 24 + (i % 24)] = 0.f;
        return;
    }
    for (int i = tid; i < 432; i += 256)
        *(float4*)&twq[4 * i] = *(const float4*)&twT[4 * i];
    xs[tid] = xin[b * 65536 + d2v[x * 256 + tid]];
    int o = tid & 31, g = tid >> 5;
    float w0 = fw[o * 3], w1 = fw[o * 3 + 1], w2 = fw[o * 3 + 2], bb = fb[o];
    float gx = x * (1.0f / 255.0f);
    __syncthreads();
    float pr[12], pi[12];
    #pragma unroll
    for (int k = 0; k < 12; ++k) { pr[k] = 0.f; pi[k] = 0.f; }
    switch (tid >> 6) {                              // quarter = wave id (uniform)
        case 0: embed_body<0>(xs, twq, h, rowbase, o, g, w0, w1, w2, bb, gx, pr, pi); break;
        case 1: embed_body<1>(xs, twq, h, rowbase, o, g, w0, w1, w2, bb, gx, pr, pi); break;
        case 2: embed_body<2>(xs, twq, h, rowbase, o, g, w0, w1, w2, bb, gx, pr, pi); break;
        default: embed_body<3>(xs, twq, h, rowbase, o, g, w0, w1, w2, bb, gx, pr, pi); break;
    }
    #pragma unroll
    for (int k = 0; k < 12; ++k) { pr[k] += __shfl_xor(pr[k], 32); pi[k] += __shfl_xor(pi[k], 32); }
    if ((tid & 32) == 0) {
        float* dst = YP + ((tid >> 6) * 32 + o) * 24;
        #pragma unroll
        for (int k = 0; k < 12; ++k) { dst[2 * k] = pr[k]; dst[2 * k + 1] = pi[k]; }
    }
    __syncthreads();
    for (int i = tid; i < 768; i += 256) {
        float s = YP[i] + YP[768 + i] + YP[1536 + i] + YP[2304 + i];
        Y[((size_t)(b * 32 + i / 24) * 288 + x) * 24 + (i % 24)] = s;
    }
}

// forward DFT along x, split into 2 x-half partials. X[half][b][c][k][ky]
__global__ __launch_bounds__(288) void k_dftx(const float* __restrict__ Y,
                                              const float* __restrict__ tw,
                                              float* __restrict__ X) {
    __shared__ __align__(16) float Ys[144 * 24];
    int c = blockIdx.x, b = blockIdx.y, half = blockIdx.z, tid = threadIdx.x;
    const float* Yb = Y + (size_t)(b * 32 + c) * 6912 + half * 3456;
    for (int i = tid; i < 864; i += 288)
        *(float4*)&Ys[4 * i] = *(const float4*)&Yb[4 * i];
    __syncthreads();
    int k = tid / 12, ky = tid % 12;
    const float* twk = tw + k * 576 + half * 288;
    float xr = 0.f, xi = 0.f;
    #pragma unroll 4
    for (int xx = 0; xx < 144; ++xx) {
        float yr = Ys[xx * 24 + 2 * ky], yi = Ys[xx * 24 + 2 * ky + 1];
        float cc = twk[2 * xx], ss = twk[2 * xx + 1];
        xr += yr * cc + yi * ss;      // e^{-i t}
        xi += yi * cc - yr * ss;
    }
    size_t oo = (size_t)half * SZ_X + ((size_t)(b * 32 + c) * 288 + tid) * 2;
    X[oo] = xr; X[oo + 1] = xi;
}

// fused spec + inverse-DFT-x (r12 kernel, kept).
__global__ __launch_bounds__(384) void k_specidft(
        const float* __restrict__ X,
        const float* __restrict__ w1r, const float* __restrict__ w1i,
        const float* __restrict__ w2r, const float* __restrict__ w2i,
        const float* __restrict__ tw, float* __restrict__ Z, int l) {
    __shared__ __align__(16) float Os[576];
    int x0 = blockIdx.x * 32, c = blockIdx.y, b = blockIdx.z, tid = threadIdx.x;
    if (tid < 288) {
        int k = tid / 12, ky = tid % 12;
        int kk = (k < KY) ? k : (k - KY);
        const float* wr = (k < KY) ? w1r : w2r;
        const float* wi = (k < KY) ? w1i : w2i;
        size_t wbase = (size_t)l * 147456 + (size_t)c * 144 + kk * 12 + ky;
        size_t xbase = (size_t)b * 18432 + (k * 12 + ky) * 2;
        float ar = 0.f, ai = 0.f;
        #pragma unroll 8
        for (int i = 0; i < 32; ++i) {
            size_t xo = xbase + (size_t)i * 576;
            float xr = X[xo]     + X[SZ_X + xo];
            float xi = X[xo + 1] + X[SZ_X + xo + 1];
            float wrr = wr[wbase + (size_t)i * 4608];
            float wii = wi[wbase + (size_t)i * 4608];
            ar += xr * wrr - xi * wii;
            ai += xr * wii + xi * wrr;
        }
        Os[2 * tid] = ar; Os[2 * tid + 1] = ai;
    }
    __syncthreads();
    int row = tid & 31, ky = tid >> 5;
    int x = x0 + row;
    float zr = 0.f, zi = 0.f;
    #pragma unroll
    for (int k = 0; k < NK; ++k) {
        float orr = Os[(k * 12 + ky) * 2], oii = Os[(k * 12 + ky) * 2 + 1];
        float cc = tw[(k * Hp + x) * 2], ss = tw[(k * Hp + x) * 2 + 1];
        zr += orr * cc - oii * ss;        // e^{+i t}
        zi += orr * ss + oii * cc;
    }
    size_t o = ((((size_t)b * Hp + x) * C + c) * KY + ky) * 2;
    Z[o] = zr; Z[o + 1] = zi;
}

// fused: 1x1 conv (weights in LDS) + inverse DFT-y + bias + gelu (in place)
// + forward DFT-y -> Y (flags bit1). r12 kernel restored VERBATIM (runtime
// flags): the r13/r14 refactor (hardcoded flags + helper split) regressed
// the measured 103 us to ~155 us — scheduling-sensitive, do not touch.
__global__ __launch_bounds__(256, 1) void k_conv(
        float* __restrict__ h, const float* __restrict__ Z,
        const float* __restrict__ cw, const float* __restrict__ cb,
        const float* __restrict__ twT, float* __restrict__ Y,
        int l, int flags) {
    __shared__ __align__(16) float hs[9216];        // [c][y] stride 288; YP alias
    __shared__ __align__(16) float twy[6912];       // [y][k][2]
    __shared__ __align__(16) float cws[32 * 33];
    __shared__ float cbs[32];
    int x = blockIdx.x, b = blockIdx.y, tid = threadIdx.x;
    size_t rowbase = (size_t)b * 2654208 + (size_t)x * 288;
    const float* hb = h + rowbase;
#if HAS_ASYNC
    #pragma unroll 1
    for (int r = 0; r < 9; ++r) {
        int i = r * 256 + tid;
        ASYNC_CP16(&hs[4 * i], hb + (size_t)(i / 72) * 82944 + (i % 72) * 4);
    }
    #pragma unroll 1
    for (int i = tid; i < 1728; i += 256)
        ASYNC_CP16(&twy[4 * i], twT + 4 * i);
#else
    for (int i = tid; i < 2304; i += 256)
        *(float4*)&hs[4 * i] = *(const float4*)&hb[(size_t)(i / 72) * 82944 + (i % 72) * 4];
    for (int i = tid; i < 1728; i += 256)
        *(float4*)&twy[4 * i] = *(const float4*)&twT[4 * i];
#endif
    for (int i = tid; i < 32 * 32; i += 256)
        cws[(i >> 5) * 33 + (i & 31)] = cw[l * 1024 + i];
    if (tid < 32) cbs[tid] = cb[l * 32 + tid];
    int o = tid & 31, g = tid >> 5;
    const float* Zr = Z + ((size_t)(b * 288 + x) * 32 + o) * 24;
    float zr[12], zi[12];
    #pragma unroll
    for (int q = 0; q < 6; ++q) {
        float4 zv = *(const float4*)&Zr[4 * q];
        zr[2*q] = zv.x; zi[2*q] = zv.y; zr[2*q+1] = zv.z; zi[2*q+1] = zv.w;
    }
    __syncthreads();
    float bias = cbs[o];
    float pr[12], pi[12];
    #pragma unroll
    for (int k = 0; k < 12; ++k) { pr[k] = 0.f; pi[k] = 0.f; }
    const int gelu_f = flags & 1, wy = flags & 2;
    #pragma unroll 1
    for (int c3 = 0; c3 < 3; ++c3) {
        int ybase = g * 36 + c3 * 12;
        float acc[12];
        #pragma unroll
        for (int j = 0; j < 12; ++j) acc[j] = bias;
        #pragma unroll 8
        for (int c = 0; c < 32; ++c) {
            float w = cws[o * 33 + c];
            const float* hr = &hs[c * 288 + ybase];
            float4 h0 = *(const float4*)&hr[0];
            float4 h1 = *(const float4*)&hr[4];
            float4 h2 = *(const float4*)&hr[8];
            acc[0] += h0.x * w; acc[1] += h0.y * w; acc[2]  += h0.z * w; acc[3]  += h0.w * w;
            acc[4] += h1.x * w; acc[5] += h1.y * w; acc[6]  += h1.z * w; acc[7]  += h1.w * w;
            acc[8] += h2.x * w; acc[9] += h2.y * w; acc[10] += h2.z * w; acc[11] += h2.w * w;
        }
        SCHED_FENCE();
        #pragma unroll
        for (int jp = 0; jp < 6; ++jp) {
            #pragma unroll
            for (int u = 0; u < 2; ++u) {
                int j = jp * 2 + u;
                int y = ybase + j;
                float tc[24];
                #pragma unroll
                for (int q = 0; q < 6; ++q) *(float4*)&tc[4 * q] = *(const float4*)&twy[y * 24 + 4 * q];
                float sp = zr[0] * tc[0] - zi[0] * tc[1];
                #pragma unroll
                for (int k = 1; k < 12; ++k) sp += 2.f * (zr[k] * tc[2*k] - zi[k] * tc[2*k+1]);
                float val = acc[j] + sp * (1.0f / 82944.0f);
                if (gelu_f) val = GELU(val);
                acc[j] = val;
                if (wy) {
                    #pragma unroll
                    for (int k = 0; k < 12; ++k) { pr[k] += val * tc[2*k]; pi[k] -= val * tc[2*k+1]; }
                }
            }
            SCHED_FENCE();
        }
        float* hw = h + rowbase + (size_t)o * 82944 + ybase;
        #pragma unroll
        for (int q = 0; q < 3; ++q)
            *(float4*)&hw[4 * q] = make_float4(acc[4*q], acc[4*q+1], acc[4*q+2], acc[4*q+3]);
        SCHED_FENCE();
    }
    if (wy) {
        #pragma unroll
        for (int k = 0; k < 12; ++k) { pr[k] += __shfl_xor(pr[k], 32); pi[k] += __shfl_xor(pi[k], 32); }
        __syncthreads();
        float* YP = hs;
        if ((tid & 32) == 0) {
            float* dst = YP + ((tid >> 6) * 32 + o) * 24;
            #pragma unroll
            for (int k = 0; k < 12; ++k) { dst[2 * k] = pr[k]; dst[2 * k + 1] = pi[k]; }
        }
        __syncthreads();
        for (int i = tid; i < 768; i += 256) {
            float s = YP[i] + YP[768 + i] + YP[1536 + i] + YP[2304 + i];
            Y[((size_t)(b * 32 + i / 24) * 288 + x) * 24 + (i % 24)] = s;
        }
    }
}

// per-pixel MLP 32 -> gelu(128) -> 2, crop, 2 pixels/thread.
// r15: layer-1 sums split into two 16-term partial chains (fp reassociation
// the compiler can't do) -> 4 independent FMA chains instead of 2 serial-32;
// f-loop unroll 2 overlaps erff with next-f FMAs. VALU-latency fix.
__global__ __launch_bounds__(256) void k_mlp(const float* __restrict__ h,
                                             const float* __restrict__ w1, const float* __restrict__ b1,
                                             const float* __restrict__ w2, const float* __restrict__ b2,
                                             float* __restrict__ tmp) {
    int bid = blockIdx.x;                          // 1024 blocks
    int b = bid >> 7;
    int x = ((bid & 127) << 1) + (threadIdx.x >> 7);
    int lane = threadIdx.x & 127;
    const float* hb = h + (size_t)b * 2654208 + (size_t)x * 288;
    float hc0[32], hc1[32];
    #pragma unroll
    for (int c = 0; c < 32; ++c) {
        hc0[c] = hb[(size_t)c * 82944 + lane];
        hc1[c] = hb[(size_t)c * 82944 + lane + 128];
    }
    float o00 = 0.f, o01 = 0.f, o10 = 0.f, o11 = 0.f;
    #pragma unroll 2
    for (int f = 0; f < 128; ++f) {
        float aL0 = 0.f, aH0 = 0.f, aL1 = 0.f, aH1 = 0.f;
        #pragma unroll
        for (int c = 0; c < 16; ++c) {
            float w = w1[f * 32 + c];
            aL0 += hc0[c] * w; aL1 += hc1[c] * w;
        }
        #pragma unroll
        for (int c = 16; c < 32; ++c) {
            float w = w1[f * 32 + c];
            aH0 += hc0[c] * w; aH1 += hc1[c] * w;
        }
        float bb = b1[f];
        float a0 = bb + (aL0 + aH0), a1 = bb + (aL1 + aH1);
        float wa = w2[f], wb = w2[128 + f];
        float g0 = GELU(a0), g1 = GELU(a1);
        o00 += g0 * wa; o01 += g0 * wb;
        o10 += g1 * wa; o11 += g1 * wb;
    }
    float bb0 = b2[0], bb1 = b2[1];
    int p0 = x * 256 + lane;
    size_t base = (size_t)b * 65536;
    *(float2*)&tmp[(base + p0) * 2]       = make_float2(o00 + bb0, o01 + bb1);
    *(float2*)&tmp[(base + p0 + 128) * 2] = make_float2(o10 + bb0, o11 + bb1);
}

// out[b][j][d] = tmp[b][v2d[j]][d]
__global__ void k_scatter(const float* __restrict__ tmp, const int* __restrict__ v2d,
                          float* __restrict__ out) {
    int id = blockIdx.x * 256 + threadIdx.x;
    int b = id >> 16; int j = id & 65535;
    int p = v2d[j];
    const float2 v = *(const float2*)(tmp + ((size_t)(b << 16) + p) * 2);
    *(float2*)(out + (size_t)id * 2) = v;
}

extern "C" void kernel_launch(void* const* d_in, const int* in_sizes, int n_in,
                              void* d_out, int out_size, void* d_ws, size_t ws_size,
                              hipStream_t stream) {
    const float* xin   = (const float*)d_in[0];
    const int*   d2v   = (const int*)  d_in[1];
    const int*   v2d   = (const int*)  d_in[2];
    const float* fc0w  = (const float*)d_in[3];
    const float* fc0b  = (const float*)d_in[4];
    const float* w1r   = (const float*)d_in[5];
    const float* w1i   = (const float*)d_in[6];
    const float* w2r   = (const float*)d_in[7];
    const float* w2i   = (const float*)d_in[8];
    const float* cw    = (const float*)d_in[9];
    const float* cb    = (const float*)d_in[10];
    const float* mw1   = (const float*)d_in[11];
    const float* mb1   = (const float*)d_in[12];
    const float* mw2   = (const float*)d_in[13];
    const float* mb2   = (const float*)d_in[14];

    float* ws  = (float*)d_ws;
    float* TW  = ws + OFF_TW;
    float* TWT = ws + OFF_TWT;
    float* H   = ws + OFF_H;
    float* Y   = ws + OFF_Y;
    float* X   = ws + OFF_X;
    float* Z   = ws + OFF_Z;
    float* T   = ws + OFF_T;

    k_tw<<<(NK * Hp + 255) / 256, 256, 0, stream>>>(TW, TWT);
    k_embed<<<dim3(Hp, Bn), 256, 0, stream>>>(xin, d2v, fc0w, fc0b, TWT, H, Y);

    for (int l = 0; l < 4; ++l) {
        k_dftx<<<dim3(32, Bn, 2), 288, 0, stream>>>(Y, TW, X);
        k_specidft<<<dim3(9, 32, Bn), 384, 0, stream>>>(X, w1r, w1i, w2r, w2i, TW, Z, l);
        // l=3: pad rows x>=256 are never read again (wy=0, MLP crops) — skip them
        k_conv<<<dim3((l != 3) ? Hp : S, Bn), 256, 0, stream>>>(H, Z, cw, cb, TWT, Y, l, (l != 3) ? 3 : 0);
    }

    k_mlp<<<1024, 256, 0, stream>>>(H, mw1, mb1, mw2, mb2, T);
    k_scatter<<<(Bn * S * S) / 256, 256, 0, stream>>>(T, v2d, (float*)d_out);
}